// Round 1
// baseline (347.219 us; speedup 1.0000x reference)
//
#include <hip/hip_runtime.h>

#define NA 4
#define NH 3
#define NHI 2
#define Bsz 32768
#define Ssz 256
#define Csz 16
#define Dsz 128
#define INsz 176

typedef __bf16 v8bf __attribute__((ext_vector_type(8)));
typedef __bf16 v4bf __attribute__((ext_vector_type(4)));
typedef float v4f __attribute__((ext_vector_type(4)));

// ---------------- encoder: enc = relu(sv @ W + b) -> bf16 [Bsz][Dsz] ----------------
__global__ __launch_bounds__(256) void enc_kernel(const float* __restrict__ sv,
                                                  const float* __restrict__ W,
                                                  const float* __restrict__ b,
                                                  __bf16* __restrict__ enc)
{
    __shared__ __bf16 xs[128][40];   // x tile: 128 rows x 32 k (pad 40)
    __shared__ __bf16 wt[128][40];   // W chunk transposed: wt[d][kk]
    const int t = threadIdx.x;
    const int r0 = blockIdx.x * 128;
    const int wv = t >> 6, lane = t & 63;
    const int m = lane & 15, quad = lane >> 4;

    v4f acc[2][8];
    for (int i = 0; i < 2; ++i)
        for (int j = 0; j < 8; ++j)
            acc[i][j] = (v4f){0.f, 0.f, 0.f, 0.f};

    for (int kc = 0; kc < 8; ++kc) {
        const int k0 = kc * 32;
        // stage x tile (fp32 -> bf16)
        {
            const int r = t >> 3, kq = (t & 7) * 4;
            for (int rr = 0; rr < 128; rr += 32) {
                float4 f = *(const float4*)(sv + (size_t)(r0 + r + rr) * Ssz + k0 + kq);
                v4bf p;
                p[0] = (__bf16)f.x; p[1] = (__bf16)f.y; p[2] = (__bf16)f.z; p[3] = (__bf16)f.w;
                *(v4bf*)&xs[r + rr][kq] = p;
            }
        }
        // stage W chunk transposed
        {
            const int kkb = t >> 5, d4 = (t & 31) * 4;
            for (int p = 0; p < 4; ++p) {
                const int kk = kkb + p * 8;
                float4 f = *(const float4*)(W + (size_t)(k0 + kk) * Dsz + d4);
                wt[d4 + 0][kk] = (__bf16)f.x;
                wt[d4 + 1][kk] = (__bf16)f.y;
                wt[d4 + 2][kk] = (__bf16)f.z;
                wt[d4 + 3][kk] = (__bf16)f.w;
            }
        }
        __syncthreads();
        v8bf af[2];
        for (int mt = 0; mt < 2; ++mt)
            af[mt] = *(const v8bf*)&xs[wv * 32 + mt * 16 + m][quad * 8];
        for (int nt = 0; nt < 8; ++nt) {
            v8bf bfv = *(const v8bf*)&wt[nt * 16 + m][quad * 8];
            for (int mt = 0; mt < 2; ++mt)
                acc[mt][nt] = __builtin_amdgcn_mfma_f32_16x16x32_bf16(af[mt], bfv, acc[mt][nt], 0, 0, 0);
        }
        __syncthreads();
    }
    for (int nt = 0; nt < 8; ++nt) {
        const int col = nt * 16 + m;
        const float bias = b[col];
        for (int mt = 0; mt < 2; ++mt)
            for (int rg = 0; rg < 4; ++rg) {
                const int row = r0 + wv * 32 + mt * 16 + quad * 4 + rg;
                float v = acc[mt][nt][rg] + bias;
                v = v > 0.f ? v : 0.f;
                enc[(size_t)row * Dsz + col] = (__bf16)v;
            }
    }
}

// ---------------- fused critic: gather -> L1 MFMA -> relu -> selected-col L2 ----------------
__global__ __launch_bounds__(256) void critic_kernel(
    const float* __restrict__ acs, const __bf16* __restrict__ enc,
    const float* __restrict__ eW1, const float* __restrict__ eb1,
    const float* __restrict__ eW2, const float* __restrict__ eb2,
    const float* __restrict__ iW1, const float* __restrict__ ib1,
    const float* __restrict__ iW2, const float* __restrict__ ib2,
    float* __restrict__ out)
{
    __shared__ union {
        struct { __bf16 xs[128][40]; __bf16 wt[128][40]; } p1;
        struct { __bf16 hs[128][136]; float w2t[16][132]; float psum[2][128]; float b2s[16]; } p2;
    } sm;

    const int t = threadIdx.x;
    const int r0 = blockIdx.x * 128;
    const int p = blockIdx.y;
    const int wv = t >> 6, lane = t & 63;
    const int m = lane & 15, quad = lane >> 4;

    int ai, hj;
    const float *W1, *b1, *W2, *b2;
    float* outp;
    if (p < 12) {
        ai = p / 3; hj = p % 3;
        const int wi = hj * NA + ai;
        W1 = eW1 + (size_t)wi * INsz * Dsz;
        b1 = eb1 + (size_t)wi * Dsz;
        W2 = eW2 + (size_t)wi * Dsz * Csz;
        b2 = eb2 + (size_t)wi * Csz;
        outp = out + (size_t)(ai * NH + hj) * Bsz;
    } else {
        const int q = p - 12;
        ai = q / 2; const int jj = q % 2; hj = jj + 1;
        const int wi = jj * NA + ai;
        W1 = iW1 + (size_t)wi * INsz * Dsz;
        b1 = ib1 + (size_t)wi * Dsz;
        W2 = iW2 + (size_t)wi * Dsz * Csz;
        b2 = ib2 + (size_t)wi * Csz;
        outp = out + (size_t)NA * NH * Bsz + (size_t)(ai * NHI + jj) * Bsz;
    }
    const int loo0 = 0 + (0 >= ai), loo1 = 1 + (1 >= ai), loo2 = 2 + (2 >= ai);
    const float* g0 = acs + (size_t)(loo0 * NH + hj) * Bsz * Csz;
    const float* g1 = acs + (size_t)(loo1 * NH + hj) * Bsz * Csz;
    const float* g2 = acs + (size_t)(loo2 * NH + hj) * Bsz * Csz;

    v4f acc[2][8];
    for (int i = 0; i < 2; ++i)
        for (int j = 0; j < 8; ++j)
            acc[i][j] = (v4f){0.f, 0.f, 0.f, 0.f};

    for (int kc = 0; kc < 6; ++kc) {
        const int k0 = kc * 32;
        // stage x tile: LOO acs gather (k<48), enc (48..175), zero pad (>=176)
        {
            const int r = t >> 3, kq = (t & 7) * 4;
            const int k = k0 + kq;
            for (int rr = 0; rr < 128; rr += 32) {
                const int row = r + rr;
                v4bf pk;
                if (k < 48) {
                    const float* g = (k < 16) ? g0 : (k < 32 ? g1 : g2);
                    float4 f = *(const float4*)(g + (size_t)(r0 + row) * Csz + (k & 15));
                    pk[0] = (__bf16)f.x; pk[1] = (__bf16)f.y; pk[2] = (__bf16)f.z; pk[3] = (__bf16)f.w;
                } else if (k < INsz) {
                    pk = *(const v4bf*)(enc + (size_t)(r0 + row) * Dsz + (k - 48));
                } else {
                    pk[0] = (__bf16)0.f; pk[1] = (__bf16)0.f; pk[2] = (__bf16)0.f; pk[3] = (__bf16)0.f;
                }
                *(v4bf*)&sm.p1.xs[row][kq] = pk;
            }
        }
        // stage W1 chunk transposed (zero pad k>=176)
        {
            const int kkb = t >> 5, d4 = (t & 31) * 4;
            for (int pp = 0; pp < 4; ++pp) {
                const int kk = kkb + pp * 8;
                const int k = k0 + kk;
                if (k < INsz) {
                    float4 f = *(const float4*)(W1 + (size_t)k * Dsz + d4);
                    sm.p1.wt[d4 + 0][kk] = (__bf16)f.x;
                    sm.p1.wt[d4 + 1][kk] = (__bf16)f.y;
                    sm.p1.wt[d4 + 2][kk] = (__bf16)f.z;
                    sm.p1.wt[d4 + 3][kk] = (__bf16)f.w;
                } else {
                    sm.p1.wt[d4 + 0][kk] = (__bf16)0.f;
                    sm.p1.wt[d4 + 1][kk] = (__bf16)0.f;
                    sm.p1.wt[d4 + 2][kk] = (__bf16)0.f;
                    sm.p1.wt[d4 + 3][kk] = (__bf16)0.f;
                }
            }
        }
        __syncthreads();
        v8bf af[2];
        for (int mt = 0; mt < 2; ++mt)
            af[mt] = *(const v8bf*)&sm.p1.xs[wv * 32 + mt * 16 + m][quad * 8];
        for (int nt = 0; nt < 8; ++nt) {
            v8bf bfv = *(const v8bf*)&sm.p1.wt[nt * 16 + m][quad * 8];
            for (int mt = 0; mt < 2; ++mt)
                acc[mt][nt] = __builtin_amdgcn_mfma_f32_16x16x32_bf16(af[mt], bfv, acc[mt][nt], 0, 0, 0);
        }
        __syncthreads();
    }

    // epilogue L1: h = relu(acc + b1) -> bf16 LDS (aliases staging buffers; barrier above done)
    for (int nt = 0; nt < 8; ++nt) {
        const int col = nt * 16 + m;
        const float bias = b1[col];
        for (int mt = 0; mt < 2; ++mt)
            for (int rg = 0; rg < 4; ++rg) {
                const int row = wv * 32 + mt * 16 + quad * 4 + rg;
                float v = acc[mt][nt][rg] + bias;
                v = v > 0.f ? v : 0.f;
                sm.p2.hs[row][col] = (__bf16)v;
            }
    }
    // stage W2 transposed (fp32) + b2
    for (int pp = 0; pp < 2; ++pp) {
        const int f4 = (t + pp * 256) * 4;      // flat into W2 [D][C]
        const int d = f4 >> 4, c = f4 & 15;
        float4 f = *(const float4*)(W2 + f4);
        sm.p2.w2t[c + 0][d] = f.x;
        sm.p2.w2t[c + 1][d] = f.y;
        sm.p2.w2t[c + 2][d] = f.z;
        sm.p2.w2t[c + 3][d] = f.w;
    }
    if (t < 16) sm.p2.b2s[t] = b2[t];
    __syncthreads();

    // layer 2: per-row dot with argmax-selected W2 column (2 threads per row)
    const int r = t & 127, half = t >> 7;
    const float* arow = acs + ((size_t)(ai * NH + hj) * Bsz + (r0 + r)) * Csz;
    float best = arow[0];
    int bi = 0;
    for (int c = 1; c < 16; ++c) {
        const float v = arow[c];
        if (v > best) { best = v; bi = c; }
    }
    float s = 0.f;
    const float* wrow = &sm.p2.w2t[bi][0];
    for (int d8 = half * 64; d8 < half * 64 + 64; d8 += 8) {
        v8bf hv = *(const v8bf*)&sm.p2.hs[r][d8];
        for (int q = 0; q < 8; ++q)
            s += (float)hv[q] * wrow[d8 + q];
    }
    sm.p2.psum[half][r] = s;
    __syncthreads();
    if (t < 128) {
        outp[r0 + t] = sm.p2.psum[0][t] + sm.p2.psum[1][t] + sm.p2.b2s[bi];
    }
}

extern "C" void kernel_launch(void* const* d_in, const int* in_sizes, int n_in,
                              void* d_out, int out_size, void* d_ws, size_t ws_size,
                              hipStream_t stream) {
    const float* sv   = (const float*)d_in[0];
    const float* acs  = (const float*)d_in[1];
    const float* encW = (const float*)d_in[2];
    const float* encb = (const float*)d_in[3];
    const float* eW1  = (const float*)d_in[4];
    const float* eb1  = (const float*)d_in[5];
    const float* eW2  = (const float*)d_in[6];
    const float* eb2  = (const float*)d_in[7];
    const float* iW1  = (const float*)d_in[8];
    const float* ib1  = (const float*)d_in[9];
    const float* iW2  = (const float*)d_in[10];
    const float* ib2  = (const float*)d_in[11];
    float* out = (float*)d_out;
    __bf16* enc = (__bf16*)d_ws;   // Bsz*Dsz bf16 = 8 MB

    hipLaunchKernelGGL(enc_kernel, dim3(Bsz / 128), dim3(256), 0, stream, sv, encW, encb, enc);
    hipLaunchKernelGGL(critic_kernel, dim3(Bsz / 128, 20), dim3(256), 0, stream,
                       acs, enc, eW1, eb1, eW2, eb2, iW1, ib1, iW2, ib2, out);
}

// Round 2
// 297.184 us; speedup vs baseline: 1.1684x; 1.1684x over previous
//
#include <hip/hip_runtime.h>

#define NA 4
#define NH 3
#define NHI 2
#define Bsz 32768
#define Ssz 256
#define Csz 16
#define Dsz 128
#define INsz 176
#define NP 20
#define KP 192   // K padded for critic L1

typedef __bf16 v8bf __attribute__((ext_vector_type(8)));
typedef float v4f __attribute__((ext_vector_type(4)));

// ---- ws layout (bytes), all 16B aligned ----
#define OFF_ENC    0                    // Bsz*Dsz*2          = 8388608
#define OFF_ACSBF  8388608              // NA*NH*Bsz*Csz*2    = 12582912
#define OFF_W1T    20971520             // NP*Dsz*KP*2        = 983040
#define OFF_ENCWT  21954560             // Dsz*Ssz*2          = 65536
#define OFF_W2T    22020096             // NP*Csz*Dsz*2       = 81920
#define OFF_AMX    22102016             // NA*NH*Bsz          = 393216
#define OFF_ZERO   22495232             // 64 B of zeros

// ---- prep ranges ----
#define N_ACS8  (NA*NH*Bsz*Csz/8)   // 786432
#define N_AMX   (NA*NH*Bsz)         // 393216
#define N_W1T   (NP*Dsz*KP)         // 491520
#define N_ENCWT (Dsz*Ssz)           // 32768
#define N_W2T   (NP*Csz*Dsz)        // 40960
#define N_ZERO  16
#define N_PREP  (N_ACS8+N_AMX+N_W1T+N_ENCWT+N_W2T+N_ZERO)  // 1744912

__global__ __launch_bounds__(256) void prep_kernel(
    const float* __restrict__ acs, const float* __restrict__ encW,
    const float* __restrict__ eW1, const float* __restrict__ iW1,
    const float* __restrict__ eW2, const float* __restrict__ iW2,
    char* __restrict__ ws)
{
    long tid = (long)blockIdx.x * 256 + threadIdx.x;

    if (tid < N_ACS8) {            // acs fp32 -> bf16, 8 elems/thread
        const float4* src = (const float4*)acs + tid * 2;
        float4 f0 = src[0], f1 = src[1];
        v8bf o;
        o[0]=(__bf16)f0.x; o[1]=(__bf16)f0.y; o[2]=(__bf16)f0.z; o[3]=(__bf16)f0.w;
        o[4]=(__bf16)f1.x; o[5]=(__bf16)f1.y; o[6]=(__bf16)f1.z; o[7]=(__bf16)f1.w;
        *((v8bf*)(ws + OFF_ACSBF) + tid) = o;
        return;
    }
    tid -= N_ACS8;
    if (tid < N_AMX) {             // argmax over C=16 (first-max)
        const float* row = acs + tid * 16;
        float best = row[0]; int bi = 0;
        #pragma unroll
        for (int c = 1; c < 16; ++c) { float v = row[c]; if (v > best) { best = v; bi = c; } }
        ((unsigned char*)(ws + OFF_AMX))[tid] = (unsigned char)bi;
        return;
    }
    tid -= N_AMX;
    if (tid < N_W1T) {             // W1 -> bf16 transposed [p][n][k], k zero-padded to 192
        int k = (int)(tid % KP);
        int rest = (int)(tid / KP);
        int n = rest & 127, p = rest >> 7;
        const float* W1;
        if (p < 12) { int ai = p / 3, hj = p % 3; W1 = eW1 + (size_t)(hj * NA + ai) * INsz * Dsz; }
        else { int qq = p - 12; int ai = qq >> 1, jj = qq & 1; W1 = iW1 + (size_t)(jj * NA + ai) * INsz * Dsz; }
        float v = (k < INsz) ? W1[(size_t)k * Dsz + n] : 0.f;
        ((__bf16*)(ws + OFF_W1T))[(size_t)p * Dsz * KP + (size_t)n * KP + k] = (__bf16)v;
        return;
    }
    tid -= N_W1T;
    if (tid < N_ENCWT) {           // encW -> bf16 transposed [n][k]
        int k = (int)(tid & 255), n = (int)(tid >> 8);
        ((__bf16*)(ws + OFF_ENCWT))[(size_t)n * Ssz + k] = (__bf16)encW[(size_t)k * Dsz + n];
        return;
    }
    tid -= N_ENCWT;
    if (tid < N_W2T) {             // W2 -> bf16 transposed [p][c][d]
        int d = (int)(tid & 127);
        int rest = (int)(tid >> 7);
        int c = rest & 15, p = rest >> 4;
        const float* W2;
        if (p < 12) { int ai = p / 3, hj = p % 3; W2 = eW2 + (size_t)(hj * NA + ai) * Dsz * Csz; }
        else { int qq = p - 12; int ai = qq >> 1, jj = qq & 1; W2 = iW2 + (size_t)(jj * NA + ai) * Dsz * Csz; }
        ((__bf16*)(ws + OFF_W2T))[(size_t)p * Csz * Dsz + (size_t)c * Dsz + d] = (__bf16)W2[(size_t)d * Csz + c];
        return;
    }
    tid -= N_W2T;
    if (tid < N_ZERO) ((float*)(ws + OFF_ZERO))[tid] = 0.f;
}

// ---------------- encoder: enc = relu(sv @ W + b) -> bf16 [Bsz][Dsz], no LDS ----------------
__global__ __launch_bounds__(256) void enc_kernel(const float* __restrict__ sv,
                                                  const float* __restrict__ encb,
                                                  char* __restrict__ ws)
{
    const int t = threadIdx.x;
    const int wv = t >> 6, lane = t & 63, m = lane & 15, q = lane >> 4;
    const int R = blockIdx.x * 64 + wv * 16 + m;       // A row for this lane
    const __bf16* wT = (const __bf16*)(ws + OFF_ENCWT);
    __bf16* enc = (__bf16*)(ws + OFF_ENC);

    v4f acc[8];
    #pragma unroll
    for (int nt = 0; nt < 8; ++nt) acc[nt] = (v4f){0.f, 0.f, 0.f, 0.f};

    const float* arow = sv + (size_t)R * Ssz + q * 8;
    const __bf16* wb = wT + (size_t)m * Ssz + q * 8;
    #pragma unroll
    for (int kc = 0; kc < 8; ++kc) {
        float4 f0 = *(const float4*)(arow + kc * 32);
        float4 f1 = *(const float4*)(arow + kc * 32 + 4);
        v8bf af;
        af[0]=(__bf16)f0.x; af[1]=(__bf16)f0.y; af[2]=(__bf16)f0.z; af[3]=(__bf16)f0.w;
        af[4]=(__bf16)f1.x; af[5]=(__bf16)f1.y; af[6]=(__bf16)f1.z; af[7]=(__bf16)f1.w;
        #pragma unroll
        for (int nt = 0; nt < 8; ++nt) {
            v8bf bf = *(const v8bf*)(wb + (size_t)nt * 16 * Ssz + kc * 32);
            acc[nt] = __builtin_amdgcn_mfma_f32_16x16x32_bf16(af, bf, acc[nt], 0, 0, 0);
        }
    }
    const int rbase = blockIdx.x * 64 + wv * 16 + q * 4;
    #pragma unroll
    for (int nt = 0; nt < 8; ++nt) {
        const float bias = encb[nt * 16 + m];
        #pragma unroll
        for (int rg = 0; rg < 4; ++rg) {
            float v = acc[nt][rg] + bias;
            v = v > 0.f ? v : 0.f;
            enc[(size_t)(rbase + rg) * Dsz + nt * 16 + m] = (__bf16)v;
        }
    }
}

// ---------------- critic: LDS-free, A-frags gathered, B-frags from preswizzled w1T ----------------
__global__ __launch_bounds__(256) void critic_kernel(
    const float* __restrict__ eb1, const float* __restrict__ eb2,
    const float* __restrict__ ib1, const float* __restrict__ ib2,
    const char* __restrict__ ws, float* __restrict__ out)
{
    const int t = threadIdx.x;
    const int r0 = blockIdx.x * 128;
    const int p = blockIdx.y;
    const int wv = t >> 6, lane = t & 63, m = lane & 15, q = lane >> 4;

    int ai, hj;
    const float *b1, *b2;
    float* outp;
    if (p < 12) {
        ai = p / 3; hj = p % 3;
        const int wi = hj * NA + ai;
        b1 = eb1 + (size_t)wi * Dsz; b2 = eb2 + (size_t)wi * Csz;
        outp = out + (size_t)(ai * NH + hj) * Bsz;
    } else {
        const int qq = p - 12; ai = qq >> 1; const int jj = qq & 1; hj = jj + 1;
        const int wi = jj * NA + ai;
        b1 = ib1 + (size_t)wi * Dsz; b2 = ib2 + (size_t)wi * Csz;
        outp = out + (size_t)NA * NH * Bsz + (size_t)(ai * NHI + jj) * Bsz;
    }

    const __bf16* acsb = (const __bf16*)(ws + OFF_ACSBF);
    const __bf16* encp = (const __bf16*)(ws + OFF_ENC);
    const __bf16* w1t  = (const __bf16*)(ws + OFF_W1T) + (size_t)p * Dsz * KP;
    const __bf16* w2t  = (const __bf16*)(ws + OFF_W2T) + (size_t)p * Csz * Dsz;
    const unsigned char* amx = (const unsigned char*)(ws + OFF_AMX) + (size_t)(ai * NH + hj) * Bsz + r0;
    const __bf16* zerop = (const __bf16*)(ws + OFF_ZERO);

    const int loo0 = 0 + (0 >= ai), loo1 = 1 + (1 >= ai), loo2 = 2 + (2 >= ai);
    const __bf16* a0p = acsb + (size_t)(loo0 * NH + hj) * Bsz * Csz;
    const __bf16* a1p = acsb + (size_t)(loo1 * NH + hj) * Bsz * Csz;
    const __bf16* a2p = acsb + (size_t)(loo2 * NH + hj) * Bsz * Csz;

    // per-lane A-fragment addresses; mt=0 row:
    const int R = r0 + wv * 32 + m;
    const __bf16* A[2][6];
    {
        A[0][0] = (q < 2) ? (a0p + (size_t)R * Csz + q * 8)        : (a1p + (size_t)R * Csz + (q - 2) * 8);
        A[0][1] = (q < 2) ? (a2p + (size_t)R * Csz + q * 8)        : (encp + (size_t)R * Dsz + (q - 2) * 8);
        A[0][2] = encp + (size_t)R * Dsz + 16 + q * 8;
        A[0][3] = encp + (size_t)R * Dsz + 48 + q * 8;
        A[0][4] = encp + (size_t)R * Dsz + 80 + q * 8;
        A[0][5] = (q < 2) ? (encp + (size_t)R * Dsz + 112 + q * 8) : zerop;
        const int s0 = Csz;                       // acs row stride (elems)
        const int s1 = (q < 2) ? Csz : Dsz;
        const int s5 = (q < 2) ? Dsz : 0;
        A[1][0] = A[0][0] + 16 * s0;
        A[1][1] = A[0][1] + 16 * s1;
        A[1][2] = A[0][2] + 16 * Dsz;
        A[1][3] = A[0][3] + 16 * Dsz;
        A[1][4] = A[0][4] + 16 * Dsz;
        A[1][5] = A[0][5] + 16 * s5;
    }

    v4f acc[2][8];
    #pragma unroll
    for (int i = 0; i < 2; ++i)
        #pragma unroll
        for (int j = 0; j < 8; ++j)
            acc[i][j] = (v4f){0.f, 0.f, 0.f, 0.f};

    const __bf16* wb = w1t + (size_t)m * KP + q * 8;
    #pragma unroll
    for (int kc = 0; kc < 6; ++kc) {
        v8bf af0 = *(const v8bf*)A[0][kc];
        v8bf af1 = *(const v8bf*)A[1][kc];
        #pragma unroll
        for (int nt = 0; nt < 8; ++nt) {
            v8bf bf = *(const v8bf*)(wb + (size_t)nt * 16 * KP + kc * 32);
            acc[0][nt] = __builtin_amdgcn_mfma_f32_16x16x32_bf16(af0, bf, acc[0][nt], 0, 0, 0);
            acc[1][nt] = __builtin_amdgcn_mfma_f32_16x16x32_bf16(af1, bf, acc[1][nt], 0, 0, 0);
        }
    }

    // epilogue: relu(acc+b1) dotted with argmax-selected W2 column, 16-lane shfl reduce
    float bias[8];
    #pragma unroll
    for (int nt = 0; nt < 8; ++nt) bias[nt] = b1[nt * 16 + m];

    #pragma unroll
    for (int mt = 0; mt < 2; ++mt) {
        const int rowbase = wv * 32 + mt * 16 + q * 4;
        float s[4];
        #pragma unroll
        for (int rg = 0; rg < 4; ++rg) {
            const int c = amx[rowbase + rg];
            const __bf16* wc = w2t + (size_t)c * Dsz + m;
            float sum = 0.f;
            #pragma unroll
            for (int nt = 0; nt < 8; ++nt) {
                float h = acc[mt][nt][rg] + bias[nt];
                h = h > 0.f ? h : 0.f;
                sum += h * (float)wc[nt * 16];
            }
            sum += __shfl_xor(sum, 1, 64);
            sum += __shfl_xor(sum, 2, 64);
            sum += __shfl_xor(sum, 4, 64);
            sum += __shfl_xor(sum, 8, 64);
            s[rg] = sum + b2[c];
        }
        if (m < 4) {
            const float v = (m == 0) ? s[0] : (m == 1) ? s[1] : (m == 2) ? s[2] : s[3];
            outp[r0 + wv * 32 + mt * 16 + q * 4 + m] = v;
        }
    }
}

extern "C" void kernel_launch(void* const* d_in, const int* in_sizes, int n_in,
                              void* d_out, int out_size, void* d_ws, size_t ws_size,
                              hipStream_t stream) {
    const float* sv   = (const float*)d_in[0];
    const float* acs  = (const float*)d_in[1];
    const float* encW = (const float*)d_in[2];
    const float* encb = (const float*)d_in[3];
    const float* eW1  = (const float*)d_in[4];
    const float* eb1  = (const float*)d_in[5];
    const float* eW2  = (const float*)d_in[6];
    const float* eb2  = (const float*)d_in[7];
    const float* iW1  = (const float*)d_in[8];
    const float* ib1  = (const float*)d_in[9];
    const float* iW2  = (const float*)d_in[10];
    const float* ib2  = (const float*)d_in[11];
    float* out = (float*)d_out;
    char* ws = (char*)d_ws;

    hipLaunchKernelGGL(prep_kernel, dim3((N_PREP + 255) / 256), dim3(256), 0, stream,
                       acs, encW, eW1, iW1, eW2, iW2, ws);
    hipLaunchKernelGGL(enc_kernel, dim3(Bsz / 64), dim3(256), 0, stream, sv, encb, ws);
    hipLaunchKernelGGL(critic_kernel, dim3(Bsz / 128, NP), dim3(256), 0, stream,
                       eb1, eb2, ib1, ib2, ws, out);
}